// Round 5
// baseline (520.356 us; speedup 1.0000x reference)
//
#include <hip/hip_runtime.h>
#include <math.h>

// GAT predictor: B=64, N=512, ATOM=34, GAT=128, HID=256, 3 layers + out.
// Round-5: attention MFMA with 2-term compensation (pH*wH + pH*wL); pL dropped
// -> LDS 17 KB -> 8 blocks/CU. B-side (Wh) keeps hi/lo bf16 split.
// ws: WhT_hi+WhT_lo [8MB+8MB] | src | dst | multi (fp32)

#define ALPHA 0.2f
#define NEG_INF -9e15f

typedef __attribute__((ext_vector_type(8))) short s16x8;   // 8 bf16 (4 VGPRs)
typedef __attribute__((ext_vector_type(4))) float f32x4;

__device__ __forceinline__ ushort bf16_rne(float f) {
  union { float f; unsigned u; } v; v.f = f;
  unsigned r = v.u + 0x7FFFu + ((v.u >> 16) & 1u);
  return (ushort)(r >> 16);
}
__device__ __forceinline__ float bf16_tof(ushort h) {
  union { unsigned u; float f; } v; v.u = ((unsigned)h) << 16;
  return v.f;
}
__device__ __forceinline__ void split_store4(
    ushort* __restrict__ ph, ushort* __restrict__ pl,
    float v0, float v1, float v2, float v3) {
  ushort h0 = bf16_rne(v0), h1 = bf16_rne(v1), h2 = bf16_rne(v2), h3 = bf16_rne(v3);
  *(ushort4*)ph = make_ushort4(h0, h1, h2, h3);
  *(ushort4*)pl = make_ushort4(bf16_rne(v0 - bf16_tof(h0)), bf16_rne(v1 - bf16_tof(h1)),
                               bf16_rne(v2 - bf16_tof(h2)), bf16_rne(v3 - bf16_tof(h3)));
}

// ---- K1: Wh = compound[32768,34]@W[34,128] -> WhT bf16 hi/lo + src/dst. ----
__global__ __launch_bounds__(256) void wh_small(
    const float* __restrict__ A, const float* __restrict__ W,
    const float* __restrict__ avec,
    ushort* __restrict__ whtH, ushort* __restrict__ whtL,
    float* __restrict__ src, float* __restrict__ dst)
{
  __shared__ float AsT[34][36];
  __shared__ float Ws[34][128];
  const int t = threadIdx.x;
  const long row0 = (long)blockIdx.x * 32;
  const int cg = t & 31, rg = t >> 5;
  {
    const int r = t >> 3, l8 = t & 7;
#pragma unroll
    for (int q = 0; q < 5; q++) {
      int k = l8 + q * 8;
      if (k < 34) AsT[k][r] = A[(row0 + r) * 34 + k];
    }
  }
  {
    int idx = t;
#pragma unroll
    for (int i = 0; i < 17; i++, idx += 256)
      Ws[idx >> 7][idx & 127] = W[idx];
  }
  __syncthreads();

  float acc[4][4];
#pragma unroll
  for (int r = 0; r < 4; r++)
#pragma unroll
    for (int c = 0; c < 4; c++) acc[r][c] = 0.f;
#pragma unroll 2
  for (int k = 0; k < 34; k++) {
    const float4 wv = *(const float4*)&Ws[k][cg * 4];
    const float4 av = *(const float4*)&AsT[k][rg * 4];
#define GFMA(r, a) \
    acc[r][0] += (a) * wv.x; acc[r][1] += (a) * wv.y; \
    acc[r][2] += (a) * wv.z; acc[r][3] += (a) * wv.w;
    GFMA(0, av.x) GFMA(1, av.y) GFMA(2, av.z) GFMA(3, av.w)
#undef GFMA
  }

  {
    const long tb = (row0 >> 9) * 65536;           // batch * 128 * 512
    const int jloc = (int)(row0 & 511) + rg * 4;
#pragma unroll
    for (int cc = 0; cc < 4; cc++) {
      const long o = tb + (long)(cg * 4 + cc) * 512 + jloc;
      split_store4(&whtH[o], &whtL[o], acc[0][cc], acc[1][cc], acc[2][cc], acc[3][cc]);
    }
  }

  const float4 a1 = *(const float4*)&avec[cg * 4];
  const float4 a2 = *(const float4*)&avec[128 + cg * 4];
#pragma unroll
  for (int r = 0; r < 4; r++) {
    float s = acc[r][0]*a1.x + acc[r][1]*a1.y + acc[r][2]*a1.z + acc[r][3]*a1.w;
    float d = acc[r][0]*a2.x + acc[r][1]*a2.y + acc[r][2]*a2.z + acc[r][3]*a2.w;
#pragma unroll
    for (int w = 1; w < 32; w <<= 1) {
      s += __shfl_xor(s, w, 64);
      d += __shfl_xor(d, w, 64);
    }
    if (cg == 0) {
      src[row0 + rg * 4 + r] = s;
      dst[row0 + rg * 4 + r] = d;
    }
  }
}

// ---- K3/K4: C = A[32768,K]@W[K,G]. whtH!=null: WhT bf16 hi/lo + src/dst out.
//      whtH==null: fp32 C store, mode 1 adds bias+leaky. ----
__global__ __launch_bounds__(256) void gemm_big(
    const float* __restrict__ A, const float* __restrict__ W,
    const float* __restrict__ bias, float* __restrict__ C,
    const float* __restrict__ avec,
    ushort* __restrict__ whtH, ushort* __restrict__ whtL,
    float* __restrict__ src, float* __restrict__ dst,
    const int K, const int Wst, const int ostride, const int mode)
{
  __shared__ float AsT[32][36];
  __shared__ float Ws[32][128];
  const int t = threadIdx.x;
  const long row0 = (long)blockIdx.x * 32;
  const int col0 = blockIdx.y * 128;
  const int cg = t & 31, rg = t >> 5;
  float acc[4][4];
#pragma unroll
  for (int r = 0; r < 4; r++)
#pragma unroll
    for (int c = 0; c < 4; c++) acc[r][c] = 0.f;

  for (int k0 = 0; k0 < K; k0 += 32) {
    {
      int idx = t;
#pragma unroll
      for (int i = 0; i < 4; i++, idx += 256) {
        int r = idx >> 5, kk = idx & 31;
        AsT[kk][r] = A[(row0 + r) * (long)K + k0 + kk];
      }
    }
    {
      int idx = t;
#pragma unroll
      for (int i = 0; i < 16; i++, idx += 256) {
        int kk = idx >> 7, g = idx & 127;
        Ws[kk][g] = W[(long)(k0 + kk) * Wst + col0 + g];
      }
    }
    __syncthreads();
#pragma unroll 4
    for (int kk = 0; kk < 32; kk++) {
      const float4 wv = *(const float4*)&Ws[kk][cg * 4];
      const float4 av = *(const float4*)&AsT[kk][rg * 4];
#define GFMA(r, a) \
      acc[r][0] += (a) * wv.x; acc[r][1] += (a) * wv.y; \
      acc[r][2] += (a) * wv.z; acc[r][3] += (a) * wv.w;
      GFMA(0, av.x) GFMA(1, av.y) GFMA(2, av.z) GFMA(3, av.w)
#undef GFMA
    }
    __syncthreads();
  }

  if (whtH) {
    const long tb = (row0 >> 9) * 65536;
    const int jloc = (int)(row0 & 511) + rg * 4;
#pragma unroll
    for (int cc = 0; cc < 4; cc++) {
      const long o = tb + (long)(cg * 4 + cc) * 512 + jloc;
      split_store4(&whtH[o], &whtL[o], acc[0][cc], acc[1][cc], acc[2][cc], acc[3][cc]);
    }
  } else {
#pragma unroll
    for (int r = 0; r < 4; r++) {
      float v0 = acc[r][0], v1 = acc[r][1], v2 = acc[r][2], v3 = acc[r][3];
      if (mode == 1) {
        const float4 bv = *(const float4*)&bias[col0 + cg * 4];
        v0 += bv.x; v1 += bv.y; v2 += bv.z; v3 += bv.w;
        v0 = v0 > 0.f ? v0 : ALPHA * v0; v1 = v1 > 0.f ? v1 : ALPHA * v1;
        v2 = v2 > 0.f ? v2 : ALPHA * v2; v3 = v3 > 0.f ? v3 : ALPHA * v3;
      }
      *(float4*)&C[(row0 + rg * 4 + r) * (long)ostride + col0 + cg * 4] =
          make_float4(v0, v1, v2, v3);
    }
  }

  if (avec) {
    const float4 a1 = *(const float4*)&avec[cg * 4];
    const float4 a2 = *(const float4*)&avec[128 + cg * 4];
#pragma unroll
    for (int r = 0; r < 4; r++) {
      float s = acc[r][0]*a1.x + acc[r][1]*a1.y + acc[r][2]*a1.z + acc[r][3]*a1.w;
      float d = acc[r][0]*a2.x + acc[r][1]*a2.y + acc[r][2]*a2.z + acc[r][3]*a2.w;
#pragma unroll
      for (int w = 1; w < 32; w <<= 1) {
        s += __shfl_xor(s, w, 64);
        d += __shfl_xor(d, w, 64);
      }
      if (cg == 0) {
        src[row0 + rg * 4 + r] = s;
        dst[row0 + rg * 4 + r] = d;
      }
    }
  }
}

// ---- K2: MFMA attention, 2-term (pH*wH + pH*wL). 16 rows x 512 j, 4 waves,
// LDS 17 KB -> 8 blocks/CU. ----
__global__ __launch_bounds__(256) void attn_mfma(
    const ushort* __restrict__ whtH, const ushort* __restrict__ whtL,
    const int*   __restrict__ adj,
    const float* __restrict__ src, const float* __restrict__ dst,
    float* __restrict__ out, const int ostride, const int ocoff)
{
  __shared__ ushort pH[16][520];   // 16.6 KB
  __shared__ float sinv[16];
  const int t = threadIdx.x;
  const long base = (long)blockIdx.y * 512;
  const int i0 = blockIdx.x * 16;

  // phase 1: scores -> softmax numerators p (bf16 into LDS), 1/sum (fp32)
  {
    const int r = t >> 4, l16 = t & 15;
    const long i = base + i0 + r;
    const float si = src[i];
    const int* __restrict__ arow = adj + i * 512;
    const float* __restrict__ drow = dst + base;
    float4 sv[8];
    float m = -INFINITY;
#pragma unroll
    for (int jj = 0; jj < 8; jj++) {
      const int j = jj * 64 + l16 * 4;
      const int4 av = *(const int4*)&arow[j];
      const float4 dv = *(const float4*)&drow[j];
      float e0 = si + dv.x, e1 = si + dv.y, e2 = si + dv.z, e3 = si + dv.w;
      e0 = e0 > 0.f ? e0 : ALPHA * e0; e1 = e1 > 0.f ? e1 : ALPHA * e1;
      e2 = e2 > 0.f ? e2 : ALPHA * e2; e3 = e3 > 0.f ? e3 : ALPHA * e3;
      e0 = av.x > 0 ? e0 : NEG_INF; e1 = av.y > 0 ? e1 : NEG_INF;
      e2 = av.z > 0 ? e2 : NEG_INF; e3 = av.w > 0 ? e3 : NEG_INF;
      sv[jj] = make_float4(e0, e1, e2, e3);
      m = fmaxf(m, fmaxf(fmaxf(e0, e1), fmaxf(e2, e3)));
    }
#pragma unroll
    for (int w = 1; w < 16; w <<= 1) m = fmaxf(m, __shfl_xor(m, w, 16));
    float sum = 0.f;
#pragma unroll
    for (int jj = 0; jj < 8; jj++) {
      const int j = jj * 64 + l16 * 4;
      float p0 = __expf(sv[jj].x - m), p1 = __expf(sv[jj].y - m);
      float p2 = __expf(sv[jj].z - m), p3 = __expf(sv[jj].w - m);
      *(ushort4*)&pH[r][j] = make_ushort4(bf16_rne(p0), bf16_rne(p1),
                                          bf16_rne(p2), bf16_rne(p3));
      sum += p0 + p1 + p2 + p3;
    }
#pragma unroll
    for (int w = 1; w < 16; w <<= 1) sum += __shfl_xor(sum, w, 16);
    if (l16 == 0) sinv[r] = 1.f / sum;
  }
  __syncthreads();

  // phase 2: wave w -> cols [w*32, w*32+32), two 16x16 tiles, K=512, 2-term
  const int wv = t >> 6, lane = t & 63;
  const int m16 = lane & 15, q = lane >> 4;
  const int n0 = wv * 32;
  const long bb = base * 128;
  const ushort* __restrict__ bH = whtH + bb + (long)(n0 + m16) * 512;
  const ushort* __restrict__ bL = whtL + bb + (long)(n0 + m16) * 512;
  f32x4 acc0 = {0.f, 0.f, 0.f, 0.f}, acc1 = {0.f, 0.f, 0.f, 0.f};
#pragma unroll 4
  for (int kb = 0; kb < 16; kb++) {
    const int k0 = kb * 32 + q * 8;
    const s16x8 aH = *(const s16x8*)&pH[m16][k0];
    const s16x8 b0H = *(const s16x8*)&bH[k0];
    const s16x8 b0L = *(const s16x8*)&bL[k0];
    const s16x8 b1H = *(const s16x8*)&bH[8192 + k0];
    const s16x8 b1L = *(const s16x8*)&bL[8192 + k0];
    acc0 = __builtin_amdgcn_mfma_f32_16x16x32_bf16(aH, b0H, acc0, 0, 0, 0);
    acc1 = __builtin_amdgcn_mfma_f32_16x16x32_bf16(aH, b1H, acc1, 0, 0, 0);
    acc0 = __builtin_amdgcn_mfma_f32_16x16x32_bf16(aH, b0L, acc0, 0, 0, 0);
    acc1 = __builtin_amdgcn_mfma_f32_16x16x32_bf16(aH, b1L, acc1, 0, 0, 0);
  }
#pragma unroll
  for (int reg = 0; reg < 4; reg++) {
    const int row = q * 4 + reg;
    const float inv = sinv[row];
    float v0 = acc0[reg] * inv, v1 = acc1[reg] * inv;
    v0 = v0 > 0.f ? v0 : expm1f(v0);
    v1 = v1 > 0.f ? v1 : expm1f(v1);
    float* op = out + (base + i0 + row) * (long)ostride + ocoff + n0 + m16;
    op[0] = v0; op[16] = v1;
  }
}

extern "C" void kernel_launch(void* const* d_in, const int* in_sizes, int n_in,
                              void* d_out, int out_size, void* d_ws, size_t ws_size,
                              hipStream_t stream) {
  const float* compound = (const float*)d_in[0];
  const int*   adj      = (const int*)d_in[1];
  const float* W_stack  = (const float*)d_in[2];
  const float* a_stack  = (const float*)d_in[3];
  const float* W_out    = (const float*)d_in[4];
  const float* a_out    = (const float*)d_in[5];
  const float* Wc       = (const float*)d_in[6];
  const float* bc       = (const float*)d_in[7];
  float* out = (float*)d_out;

  ushort* whtH = (ushort*)d_ws;                       // 8 MB
  ushort* whtL = whtH + 4194304;                      // 8 MB
  float* f     = (float*)d_ws;
  float* src   = f + 4194304;
  float* dstv  = f + 4194304 + 32768;
  float* multi = f + 4194304 + 65536;
  float* x     = multi;

  for (int l = 0; l < 3; l++) {
    wh_small<<<1024, 256, 0, stream>>>(
        compound, W_stack + (long)l * 34 * 128, a_stack + (long)l * 256,
        whtH, whtL, src, dstv);
    attn_mfma<<<dim3(32, 64), 256, 0, stream>>>(
        whtH, whtL, adj, src, dstv, multi, 384, l * 128);
  }
  gemm_big<<<dim3(1024, 1), 256, 0, stream>>>(
      multi, W_out, nullptr, nullptr, a_out, whtH, whtL, src, dstv, 384, 128, 0, 0);
  attn_mfma<<<dim3(32, 64), 256, 0, stream>>>(
      whtH, whtL, adj, src, dstv, x, 128, 0);
  gemm_big<<<dim3(1024, 2), 256, 0, stream>>>(
      x, Wc, bc, out, nullptr, nullptr, nullptr, nullptr, nullptr, 128, 256, 256, 1);
}

// Round 6
// 452.711 us; speedup vs baseline: 1.1494x; 1.1494x over previous
//
#include <hip/hip_runtime.h>
#include <math.h>

// GAT predictor: B=64, N=512, ATOM=34, GAT=128, HID=256, 3 layers + out.
// Round-6: attention decoupled into scores (stream, writes normalized bf16 P)
// + agg (batched MFMA GEMM P@WhT, one barrier). 2-term B-side hi/lo compensation.
// ws layout (bytes):
//   whtH 16.8MB@0 | whtL @8MB | Pg (bf16, 64*512*512) @16MB (33.6MB)
//   src/dst floats @50.3MB | multi (fp32 12.58M floats) @50.6MB   ~101MB total

#define ALPHA 0.2f
#define NEG_INF -9e15f

typedef __attribute__((ext_vector_type(8))) short s16x8;   // 8 bf16 (4 VGPRs)
typedef __attribute__((ext_vector_type(4))) float f32x4;

__device__ __forceinline__ ushort bf16_rne(float f) {
  union { float f; unsigned u; } v; v.f = f;
  unsigned r = v.u + 0x7FFFu + ((v.u >> 16) & 1u);
  return (ushort)(r >> 16);
}
__device__ __forceinline__ float bf16_tof(ushort h) {
  union { unsigned u; float f; } v; v.u = ((unsigned)h) << 16;
  return v.f;
}
__device__ __forceinline__ void split_store4(
    ushort* __restrict__ ph, ushort* __restrict__ pl,
    float v0, float v1, float v2, float v3) {
  ushort h0 = bf16_rne(v0), h1 = bf16_rne(v1), h2 = bf16_rne(v2), h3 = bf16_rne(v3);
  *(ushort4*)ph = make_ushort4(h0, h1, h2, h3);
  *(ushort4*)pl = make_ushort4(bf16_rne(v0 - bf16_tof(h0)), bf16_rne(v1 - bf16_tof(h1)),
                               bf16_rne(v2 - bf16_tof(h2)), bf16_rne(v3 - bf16_tof(h3)));
}

// ---- K1: Wh = compound[32768,34]@W[34,128] -> WhT bf16 hi/lo + src/dst. ----
__global__ __launch_bounds__(256) void wh_small(
    const float* __restrict__ A, const float* __restrict__ W,
    const float* __restrict__ avec,
    ushort* __restrict__ whtH, ushort* __restrict__ whtL,
    float* __restrict__ src, float* __restrict__ dst)
{
  __shared__ float AsT[34][36];
  __shared__ float Ws[34][128];
  const int t = threadIdx.x;
  const long row0 = (long)blockIdx.x * 32;
  const int cg = t & 31, rg = t >> 5;
  {
    const int r = t >> 3, l8 = t & 7;
#pragma unroll
    for (int q = 0; q < 5; q++) {
      int k = l8 + q * 8;
      if (k < 34) AsT[k][r] = A[(row0 + r) * 34 + k];
    }
  }
  {
    int idx = t;
#pragma unroll
    for (int i = 0; i < 17; i++, idx += 256)
      Ws[idx >> 7][idx & 127] = W[idx];
  }
  __syncthreads();

  float acc[4][4];
#pragma unroll
  for (int r = 0; r < 4; r++)
#pragma unroll
    for (int c = 0; c < 4; c++) acc[r][c] = 0.f;
#pragma unroll 2
  for (int k = 0; k < 34; k++) {
    const float4 wv = *(const float4*)&Ws[k][cg * 4];
    const float4 av = *(const float4*)&AsT[k][rg * 4];
#define GFMA(r, a) \
    acc[r][0] += (a) * wv.x; acc[r][1] += (a) * wv.y; \
    acc[r][2] += (a) * wv.z; acc[r][3] += (a) * wv.w;
    GFMA(0, av.x) GFMA(1, av.y) GFMA(2, av.z) GFMA(3, av.w)
#undef GFMA
  }

  {
    const long tb = (row0 >> 9) * 65536;           // batch * 128 * 512
    const int jloc = (int)(row0 & 511) + rg * 4;
#pragma unroll
    for (int cc = 0; cc < 4; cc++) {
      const long o = tb + (long)(cg * 4 + cc) * 512 + jloc;
      split_store4(&whtH[o], &whtL[o], acc[0][cc], acc[1][cc], acc[2][cc], acc[3][cc]);
    }
  }

  const float4 a1 = *(const float4*)&avec[cg * 4];
  const float4 a2 = *(const float4*)&avec[128 + cg * 4];
#pragma unroll
  for (int r = 0; r < 4; r++) {
    float s = acc[r][0]*a1.x + acc[r][1]*a1.y + acc[r][2]*a1.z + acc[r][3]*a1.w;
    float d = acc[r][0]*a2.x + acc[r][1]*a2.y + acc[r][2]*a2.z + acc[r][3]*a2.w;
#pragma unroll
    for (int w = 1; w < 32; w <<= 1) {
      s += __shfl_xor(s, w, 64);
      d += __shfl_xor(d, w, 64);
    }
    if (cg == 0) {
      src[row0 + rg * 4 + r] = s;
      dst[row0 + rg * 4 + r] = d;
    }
  }
}

// ---- K3/K4: C = A[32768,K]@W[K,G]. whtH!=null: WhT bf16 hi/lo + src/dst out.
//      whtH==null: fp32 C store, mode 1 adds bias+leaky. ----
__global__ __launch_bounds__(256) void gemm_big(
    const float* __restrict__ A, const float* __restrict__ W,
    const float* __restrict__ bias, float* __restrict__ C,
    const float* __restrict__ avec,
    ushort* __restrict__ whtH, ushort* __restrict__ whtL,
    float* __restrict__ src, float* __restrict__ dst,
    const int K, const int Wst, const int ostride, const int mode)
{
  __shared__ float AsT[32][36];
  __shared__ float Ws[32][128];
  const int t = threadIdx.x;
  const long row0 = (long)blockIdx.x * 32;
  const int col0 = blockIdx.y * 128;
  const int cg = t & 31, rg = t >> 5;
  float acc[4][4];
#pragma unroll
  for (int r = 0; r < 4; r++)
#pragma unroll
    for (int c = 0; c < 4; c++) acc[r][c] = 0.f;

  for (int k0 = 0; k0 < K; k0 += 32) {
    {
      int idx = t;
#pragma unroll
      for (int i = 0; i < 4; i++, idx += 256) {
        int r = idx >> 5, kk = idx & 31;
        AsT[kk][r] = A[(row0 + r) * (long)K + k0 + kk];
      }
    }
    {
      int idx = t;
#pragma unroll
      for (int i = 0; i < 16; i++, idx += 256) {
        int kk = idx >> 7, g = idx & 127;
        Ws[kk][g] = W[(long)(k0 + kk) * Wst + col0 + g];
      }
    }
    __syncthreads();
#pragma unroll 4
    for (int kk = 0; kk < 32; kk++) {
      const float4 wv = *(const float4*)&Ws[kk][cg * 4];
      const float4 av = *(const float4*)&AsT[kk][rg * 4];
#define GFMA(r, a) \
      acc[r][0] += (a) * wv.x; acc[r][1] += (a) * wv.y; \
      acc[r][2] += (a) * wv.z; acc[r][3] += (a) * wv.w;
      GFMA(0, av.x) GFMA(1, av.y) GFMA(2, av.z) GFMA(3, av.w)
#undef GFMA
    }
    __syncthreads();
  }

  if (whtH) {
    const long tb = (row0 >> 9) * 65536;
    const int jloc = (int)(row0 & 511) + rg * 4;
#pragma unroll
    for (int cc = 0; cc < 4; cc++) {
      const long o = tb + (long)(cg * 4 + cc) * 512 + jloc;
      split_store4(&whtH[o], &whtL[o], acc[0][cc], acc[1][cc], acc[2][cc], acc[3][cc]);
    }
  } else {
#pragma unroll
    for (int r = 0; r < 4; r++) {
      float v0 = acc[r][0], v1 = acc[r][1], v2 = acc[r][2], v3 = acc[r][3];
      if (mode == 1) {
        const float4 bv = *(const float4*)&bias[col0 + cg * 4];
        v0 += bv.x; v1 += bv.y; v2 += bv.z; v3 += bv.w;
        v0 = v0 > 0.f ? v0 : ALPHA * v0; v1 = v1 > 0.f ? v1 : ALPHA * v1;
        v2 = v2 > 0.f ? v2 : ALPHA * v2; v3 = v3 > 0.f ? v3 : ALPHA * v3;
      }
      *(float4*)&C[(row0 + rg * 4 + r) * (long)ostride + col0 + cg * 4] =
          make_float4(v0, v1, v2, v3);
    }
  }

  if (avec) {
    const float4 a1 = *(const float4*)&avec[cg * 4];
    const float4 a2 = *(const float4*)&avec[128 + cg * 4];
#pragma unroll
    for (int r = 0; r < 4; r++) {
      float s = acc[r][0]*a1.x + acc[r][1]*a1.y + acc[r][2]*a1.z + acc[r][3]*a1.w;
      float d = acc[r][0]*a2.x + acc[r][1]*a2.y + acc[r][2]*a2.z + acc[r][3]*a2.w;
#pragma unroll
      for (int w = 1; w < 32; w <<= 1) {
        s += __shfl_xor(s, w, 64);
        d += __shfl_xor(d, w, 64);
      }
      if (cg == 0) {
        src[row0 + rg * 4 + r] = s;
        dst[row0 + rg * 4 + r] = d;
      }
    }
  }
}

// ---- K2a: scores -> normalized softmax P (bf16) to global. No LDS. ----
// 16 rows/block, 16 threads/row, 32 j each.
__global__ __launch_bounds__(256) void scores_kernel(
    const int* __restrict__ adj,
    const float* __restrict__ src, const float* __restrict__ dst,
    ushort* __restrict__ Pg)     // [B*512, 512] row-major bf16, pre-normalized
{
  const int t = threadIdx.x;
  const long base = (long)blockIdx.y * 512;
  const int i0 = blockIdx.x * 16;
  const int r = t >> 4, l16 = t & 15;
  const long i = base + i0 + r;
  const float si = src[i];
  const int* __restrict__ arow = adj + i * 512;
  const float* __restrict__ drow = dst + base;
  float4 sv[8];
  float m = -INFINITY;
#pragma unroll
  for (int jj = 0; jj < 8; jj++) {
    const int j = jj * 64 + l16 * 4;
    const int4 av = *(const int4*)&arow[j];
    const float4 dv = *(const float4*)&drow[j];
    float e0 = si + dv.x, e1 = si + dv.y, e2 = si + dv.z, e3 = si + dv.w;
    e0 = fmaxf(e0, ALPHA * e0); e1 = fmaxf(e1, ALPHA * e1);   // leaky, alpha<1
    e2 = fmaxf(e2, ALPHA * e2); e3 = fmaxf(e3, ALPHA * e3);
    e0 = av.x > 0 ? e0 : NEG_INF; e1 = av.y > 0 ? e1 : NEG_INF;
    e2 = av.z > 0 ? e2 : NEG_INF; e3 = av.w > 0 ? e3 : NEG_INF;
    sv[jj] = make_float4(e0, e1, e2, e3);
    m = fmaxf(m, fmaxf(fmaxf(e0, e1), fmaxf(e2, e3)));
  }
#pragma unroll
  for (int w = 1; w < 16; w <<= 1) m = fmaxf(m, __shfl_xor(m, w, 16));
  float sum = 0.f;
#pragma unroll
  for (int jj = 0; jj < 8; jj++) {
    float p0 = __expf(sv[jj].x - m), p1 = __expf(sv[jj].y - m);
    float p2 = __expf(sv[jj].z - m), p3 = __expf(sv[jj].w - m);
    sv[jj] = make_float4(p0, p1, p2, p3);
    sum += p0 + p1 + p2 + p3;
  }
#pragma unroll
  for (int w = 1; w < 16; w <<= 1) sum += __shfl_xor(sum, w, 16);
  const float inv = 1.f / sum;
  ushort* __restrict__ prow = Pg + i * 512;
#pragma unroll
  for (int jj = 0; jj < 8; jj++) {
    const int j = jj * 64 + l16 * 4;
    *(ushort4*)&prow[j] = make_ushort4(
        bf16_rne(sv[jj].x * inv), bf16_rne(sv[jj].y * inv),
        bf16_rne(sv[jj].z * inv), bf16_rne(sv[jj].w * inv));
  }
}

// ---- K2b: out = elu(P @ WhT^T), batched MFMA GEMM. 32 rows x 128 cols/block,
// A-tile staged once (33 KB LDS, one barrier), then pure MFMA + L2 stream. ----
__global__ __launch_bounds__(256, 4) void agg_kernel(
    const ushort* __restrict__ Pg,
    const ushort* __restrict__ whtH, const ushort* __restrict__ whtL,
    float* __restrict__ out, const int ostride, const int ocoff)
{
  __shared__ ushort As[32][520];   // rows padded: 1040 B stride, 16B-aligned
  const int t = threadIdx.x;
  const long base = (long)blockIdx.y * 512;
  const int i0 = blockIdx.x * 32;

  {
    const ushort* __restrict__ Ps = Pg + (base + i0) * 512;
#pragma unroll
    for (int it = 0; it < 8; it++) {
      const int idx = t + it * 256;             // 2048 x 16B = 32 KB
      const int row = idx >> 6, c8 = idx & 63;
      *(s16x8*)&As[row][c8 * 8] = *(const s16x8*)&Ps[idx * 8];
    }
  }
  __syncthreads();

  const int wv = t >> 6, lane = t & 63;
  const int m16 = lane & 15, q = lane >> 4;
  const int n0 = wv * 32;
  const long bb = base * 128;
  const ushort* __restrict__ bH = whtH + bb + (long)(n0 + m16) * 512;
  const ushort* __restrict__ bL = whtL + bb + (long)(n0 + m16) * 512;
  f32x4 acc00 = {0.f,0.f,0.f,0.f}, acc01 = {0.f,0.f,0.f,0.f};
  f32x4 acc10 = {0.f,0.f,0.f,0.f}, acc11 = {0.f,0.f,0.f,0.f};
#pragma unroll 2
  for (int kb = 0; kb < 16; kb++) {
    const int k0 = kb * 32 + q * 8;
    const s16x8 a0 = *(const s16x8*)&As[m16][k0];
    const s16x8 a1 = *(const s16x8*)&As[16 + m16][k0];
    const s16x8 b0H = *(const s16x8*)&bH[k0];
    const s16x8 b0L = *(const s16x8*)&bL[k0];
    const s16x8 b1H = *(const s16x8*)&bH[8192 + k0];
    const s16x8 b1L = *(const s16x8*)&bL[8192 + k0];
    acc00 = __builtin_amdgcn_mfma_f32_16x16x32_bf16(a0, b0H, acc00, 0, 0, 0);
    acc01 = __builtin_amdgcn_mfma_f32_16x16x32_bf16(a0, b1H, acc01, 0, 0, 0);
    acc10 = __builtin_amdgcn_mfma_f32_16x16x32_bf16(a1, b0H, acc10, 0, 0, 0);
    acc11 = __builtin_amdgcn_mfma_f32_16x16x32_bf16(a1, b1H, acc11, 0, 0, 0);
    acc00 = __builtin_amdgcn_mfma_f32_16x16x32_bf16(a0, b0L, acc00, 0, 0, 0);
    acc01 = __builtin_amdgcn_mfma_f32_16x16x32_bf16(a0, b1L, acc01, 0, 0, 0);
    acc10 = __builtin_amdgcn_mfma_f32_16x16x32_bf16(a1, b0L, acc10, 0, 0, 0);
    acc11 = __builtin_amdgcn_mfma_f32_16x16x32_bf16(a1, b1L, acc11, 0, 0, 0);
  }
  // C/D: row(i) = q*4+reg (+16 for mtile1), col(c) = n0+m16 (+16 for ntile1)
#pragma unroll
  for (int reg = 0; reg < 4; reg++) {
    const int row = q * 4 + reg;
    float v00 = acc00[reg], v01 = acc01[reg], v10 = acc10[reg], v11 = acc11[reg];
    v00 = v00 > 0.f ? v00 : expm1f(v00);
    v01 = v01 > 0.f ? v01 : expm1f(v01);
    v10 = v10 > 0.f ? v10 : expm1f(v10);
    v11 = v11 > 0.f ? v11 : expm1f(v11);
    float* o0 = out + (base + i0 + row) * (long)ostride + ocoff + n0 + m16;
    float* o1 = out + (base + i0 + 16 + row) * (long)ostride + ocoff + n0 + m16;
    o0[0] = v00; o0[16] = v01;
    o1[0] = v10; o1[16] = v11;
  }
}

extern "C" void kernel_launch(void* const* d_in, const int* in_sizes, int n_in,
                              void* d_out, int out_size, void* d_ws, size_t ws_size,
                              hipStream_t stream) {
  const float* compound = (const float*)d_in[0];
  const int*   adj      = (const int*)d_in[1];
  const float* W_stack  = (const float*)d_in[2];
  const float* a_stack  = (const float*)d_in[3];
  const float* W_out    = (const float*)d_in[4];
  const float* a_out    = (const float*)d_in[5];
  const float* Wc       = (const float*)d_in[6];
  const float* bc       = (const float*)d_in[7];
  float* out = (float*)d_out;

  ushort* whtH = (ushort*)d_ws;                       // 8 MB
  ushort* whtL = whtH + 4194304;                      // 8 MB
  ushort* Pg   = whtL + 4194304;                      // 33.6 MB (64*512*512 bf16)
  float* f     = (float*)d_ws;
  float* src   = f + 12582912;                        // after whtH/L + Pg
  float* dstv  = src + 32768;
  float* multi = dstv + 32768;                        // 12,582,912 floats
  float* x     = multi;

  for (int l = 0; l < 3; l++) {
    wh_small<<<1024, 256, 0, stream>>>(
        compound, W_stack + (long)l * 34 * 128, a_stack + (long)l * 256,
        whtH, whtL, src, dstv);
    scores_kernel<<<dim3(32, 64), 256, 0, stream>>>(adj, src, dstv, Pg);
    agg_kernel<<<dim3(16, 64), 256, 0, stream>>>(
        Pg, whtH, whtL, multi, 384, l * 128);
  }
  gemm_big<<<dim3(1024, 1), 256, 0, stream>>>(
      multi, W_out, nullptr, nullptr, a_out, whtH, whtL, src, dstv, 384, 128, 0, 0);
  scores_kernel<<<dim3(32, 64), 256, 0, stream>>>(adj, src, dstv, Pg);
  agg_kernel<<<dim3(16, 64), 256, 0, stream>>>(
      Pg, whtH, whtL, x, 128, 0);
  gemm_big<<<dim3(1024, 2), 256, 0, stream>>>(
      x, Wc, bc, out, nullptr, nullptr, nullptr, nullptr, nullptr, 128, 256, 256, 1);
}

// Round 7
// 411.166 us; speedup vs baseline: 1.2656x; 1.1010x over previous
//
#include <hip/hip_runtime.h>
#include <math.h>

// GAT predictor: B=64, N=512, ATOM=34, GAT=128, HID=256, 3 layers + out.
// Round-7: (1) remaining fp32 GEMMs -> MFMA (A split to bf16 hi/lo during LDS
// staging; W pre-transposed/split by wt_prep); (2) adj packed to bitmask once
// (scores reads 2MB instead of 67MB). 3-term compensation everywhere (~2^-18).
// ws: whtH 8MB | whtL 8MB | Pg 33.5MB (also hosts WoutT between agg-3/scores-4)
//     src/dst | multi 50MB (x aliases head; WcT parked at +5M floats)
// d_out head hosts the 2.1MB adj bitmask until the final GEMM overwrites it.

#define ALPHA 0.2f
#define NEG_INF -9e15f

typedef __attribute__((ext_vector_type(8))) short s16x8;   // 8 bf16 (4 VGPRs)
typedef __attribute__((ext_vector_type(4))) float f32x4;

__device__ __forceinline__ ushort bf16_rne(float f) {
  union { float f; unsigned u; } v; v.f = f;
  unsigned r = v.u + 0x7FFFu + ((v.u >> 16) & 1u);
  return (ushort)(r >> 16);
}
__device__ __forceinline__ float bf16_tof(ushort h) {
  union { unsigned u; float f; } v; v.u = ((unsigned)h) << 16;
  return v.f;
}
__device__ __forceinline__ void split_store4(
    ushort* __restrict__ ph, ushort* __restrict__ pl,
    float v0, float v1, float v2, float v3) {
  ushort h0 = bf16_rne(v0), h1 = bf16_rne(v1), h2 = bf16_rne(v2), h3 = bf16_rne(v3);
  *(ushort4*)ph = make_ushort4(h0, h1, h2, h3);
  *(ushort4*)pl = make_ushort4(bf16_rne(v0 - bf16_tof(h0)), bf16_rne(v1 - bf16_tof(h1)),
                               bf16_rne(v2 - bf16_tof(h2)), bf16_rne(v3 - bf16_tof(h3)));
}

// ---- K0: pack adj>0 into bitmask [32768][16] uint. ----
__global__ __launch_bounds__(256) void maskprep(
    const int* __restrict__ adj, unsigned* __restrict__ mask)
{
  const int gid = blockIdx.x * 256 + threadIdx.x;       // 524288 words
  const int4* __restrict__ p = (const int4*)(adj + (long)gid * 32);
  unsigned m = 0;
#pragma unroll
  for (int k = 0; k < 8; k++) {
    const int4 v = p[k];
    m |= (v.x > 0 ? 1u : 0u) << (4 * k);
    m |= (v.y > 0 ? 1u : 0u) << (4 * k + 1);
    m |= (v.z > 0 ? 1u : 0u) << (4 * k + 2);
    m |= (v.w > 0 ? 1u : 0u) << (4 * k + 3);
  }
  mask[gid] = m;
}

// ---- transpose + hi/lo split a weight matrix: W[K,N] fp32 -> TH/TL[N][K]. ----
__global__ __launch_bounds__(256) void wt_prep(
    const float* __restrict__ W, ushort* __restrict__ TH, ushort* __restrict__ TL,
    const int Kd, const int Nd)
{
  const int idx = blockIdx.x * 256 + threadIdx.x;
  if (idx >= Kd * Nd) return;
  const int k = idx / Nd, n = idx % Nd;
  const float v = W[idx];
  const ushort h = bf16_rne(v);
  TH[(long)n * Kd + k] = h;
  TL[(long)n * Kd + k] = bf16_rne(v - bf16_tof(h));
}

// ---- K1: Wh = compound[32768,34]@W[34,128] -> WhT bf16 hi/lo + src/dst. ----
__global__ __launch_bounds__(256) void wh_small(
    const float* __restrict__ A, const float* __restrict__ W,
    const float* __restrict__ avec,
    ushort* __restrict__ whtH, ushort* __restrict__ whtL,
    float* __restrict__ src, float* __restrict__ dst)
{
  __shared__ float AsT[34][36];
  __shared__ float Ws[34][128];
  const int t = threadIdx.x;
  const long row0 = (long)blockIdx.x * 32;
  const int cg = t & 31, rg = t >> 5;
  {
    const int r = t >> 3, l8 = t & 7;
#pragma unroll
    for (int q = 0; q < 5; q++) {
      int k = l8 + q * 8;
      if (k < 34) AsT[k][r] = A[(row0 + r) * 34 + k];
    }
  }
  {
    int idx = t;
#pragma unroll
    for (int i = 0; i < 17; i++, idx += 256)
      Ws[idx >> 7][idx & 127] = W[idx];
  }
  __syncthreads();

  float acc[4][4];
#pragma unroll
  for (int r = 0; r < 4; r++)
#pragma unroll
    for (int c = 0; c < 4; c++) acc[r][c] = 0.f;
#pragma unroll 2
  for (int k = 0; k < 34; k++) {
    const float4 wv = *(const float4*)&Ws[k][cg * 4];
    const float4 av = *(const float4*)&AsT[k][rg * 4];
#define GFMA(r, a) \
    acc[r][0] += (a) * wv.x; acc[r][1] += (a) * wv.y; \
    acc[r][2] += (a) * wv.z; acc[r][3] += (a) * wv.w;
    GFMA(0, av.x) GFMA(1, av.y) GFMA(2, av.z) GFMA(3, av.w)
#undef GFMA
  }

  {
    const long tb = (row0 >> 9) * 65536;
    const int jloc = (int)(row0 & 511) + rg * 4;
#pragma unroll
    for (int cc = 0; cc < 4; cc++) {
      const long o = tb + (long)(cg * 4 + cc) * 512 + jloc;
      split_store4(&whtH[o], &whtL[o], acc[0][cc], acc[1][cc], acc[2][cc], acc[3][cc]);
    }
  }

  const float4 a1 = *(const float4*)&avec[cg * 4];
  const float4 a2 = *(const float4*)&avec[128 + cg * 4];
#pragma unroll
  for (int r = 0; r < 4; r++) {
    float s = acc[r][0]*a1.x + acc[r][1]*a1.y + acc[r][2]*a1.z + acc[r][3]*a1.w;
    float d = acc[r][0]*a2.x + acc[r][1]*a2.y + acc[r][2]*a2.z + acc[r][3]*a2.w;
#pragma unroll
    for (int w = 1; w < 32; w <<= 1) {
      s += __shfl_xor(s, w, 64);
      d += __shfl_xor(d, w, 64);
    }
    if (cg == 0) {
      src[row0 + rg * 4 + r] = s;
      dst[row0 + rg * 4 + r] = d;
    }
  }
}

// ---- K2a: scores -> normalized softmax P (bf16) to global. Bitmask adj. ----
__global__ __launch_bounds__(256) void scores_kernel(
    const unsigned* __restrict__ mask,
    const float* __restrict__ src, const float* __restrict__ dst,
    ushort* __restrict__ Pg)
{
  const int t = threadIdx.x;
  const long base = (long)blockIdx.y * 512;
  const int i0 = blockIdx.x * 16;
  const int r = t >> 4, l16 = t & 15;
  const long i = base + i0 + r;
  const float si = src[i];
  const unsigned* __restrict__ mrow = mask + i * 16;
  const float* __restrict__ drow = dst + base;
  const int sh = (l16 & 7) * 4;
  float4 sv[8];
  float m = -INFINITY;
#pragma unroll
  for (int jj = 0; jj < 8; jj++) {
    const int j = jj * 64 + l16 * 4;
    const unsigned mw = mrow[2 * jj + (l16 >> 3)];
    const float4 dv = *(const float4*)&drow[j];
    float e0 = si + dv.x, e1 = si + dv.y, e2 = si + dv.z, e3 = si + dv.w;
    e0 = fmaxf(e0, ALPHA * e0); e1 = fmaxf(e1, ALPHA * e1);
    e2 = fmaxf(e2, ALPHA * e2); e3 = fmaxf(e3, ALPHA * e3);
    e0 = ((mw >> sh) & 1) ? e0 : NEG_INF;
    e1 = ((mw >> (sh + 1)) & 1) ? e1 : NEG_INF;
    e2 = ((mw >> (sh + 2)) & 1) ? e2 : NEG_INF;
    e3 = ((mw >> (sh + 3)) & 1) ? e3 : NEG_INF;
    sv[jj] = make_float4(e0, e1, e2, e3);
    m = fmaxf(m, fmaxf(fmaxf(e0, e1), fmaxf(e2, e3)));
  }
#pragma unroll
  for (int w = 1; w < 16; w <<= 1) m = fmaxf(m, __shfl_xor(m, w, 16));
  float sum = 0.f;
#pragma unroll
  for (int jj = 0; jj < 8; jj++) {
    float p0 = __expf(sv[jj].x - m), p1 = __expf(sv[jj].y - m);
    float p2 = __expf(sv[jj].z - m), p3 = __expf(sv[jj].w - m);
    sv[jj] = make_float4(p0, p1, p2, p3);
    sum += p0 + p1 + p2 + p3;
  }
#pragma unroll
  for (int w = 1; w < 16; w <<= 1) sum += __shfl_xor(sum, w, 16);
  const float inv = 1.f / sum;
  ushort* __restrict__ prow = Pg + i * 512;
#pragma unroll
  for (int jj = 0; jj < 8; jj++) {
    const int j = jj * 64 + l16 * 4;
    *(ushort4*)&prow[j] = make_ushort4(
        bf16_rne(sv[jj].x * inv), bf16_rne(sv[jj].y * inv),
        bf16_rne(sv[jj].z * inv), bf16_rne(sv[jj].w * inv));
  }
}

// ---- K2b: out = elu(P @ WhT^T), batched MFMA GEMM (round-6 proven). ----
__global__ __launch_bounds__(256, 4) void agg_kernel(
    const ushort* __restrict__ Pg,
    const ushort* __restrict__ whtH, const ushort* __restrict__ whtL,
    float* __restrict__ out, const int ostride, const int ocoff)
{
  __shared__ ushort As[32][520];
  const int t = threadIdx.x;
  const long base = (long)blockIdx.y * 512;
  const int i0 = blockIdx.x * 32;
  {
    const ushort* __restrict__ Ps = Pg + (base + i0) * 512;
#pragma unroll
    for (int it = 0; it < 8; it++) {
      const int idx = t + it * 256;
      const int row = idx >> 6, c8 = idx & 63;
      *(s16x8*)&As[row][c8 * 8] = *(const s16x8*)&Ps[idx * 8];
    }
  }
  __syncthreads();

  const int wv = t >> 6, lane = t & 63;
  const int m16 = lane & 15, q = lane >> 4;
  const int n0 = wv * 32;
  const long bb = base * 128;
  const ushort* __restrict__ bH = whtH + bb + (long)(n0 + m16) * 512;
  const ushort* __restrict__ bL = whtL + bb + (long)(n0 + m16) * 512;
  f32x4 acc00 = {0.f,0.f,0.f,0.f}, acc01 = {0.f,0.f,0.f,0.f};
  f32x4 acc10 = {0.f,0.f,0.f,0.f}, acc11 = {0.f,0.f,0.f,0.f};
#pragma unroll 2
  for (int kb = 0; kb < 16; kb++) {
    const int k0 = kb * 32 + q * 8;
    const s16x8 a0 = *(const s16x8*)&As[m16][k0];
    const s16x8 a1 = *(const s16x8*)&As[16 + m16][k0];
    const s16x8 b0H = *(const s16x8*)&bH[k0];
    const s16x8 b0L = *(const s16x8*)&bL[k0];
    const s16x8 b1H = *(const s16x8*)&bH[8192 + k0];
    const s16x8 b1L = *(const s16x8*)&bL[8192 + k0];
    acc00 = __builtin_amdgcn_mfma_f32_16x16x32_bf16(a0, b0H, acc00, 0, 0, 0);
    acc01 = __builtin_amdgcn_mfma_f32_16x16x32_bf16(a0, b1H, acc01, 0, 0, 0);
    acc10 = __builtin_amdgcn_mfma_f32_16x16x32_bf16(a1, b0H, acc10, 0, 0, 0);
    acc11 = __builtin_amdgcn_mfma_f32_16x16x32_bf16(a1, b1H, acc11, 0, 0, 0);
    acc00 = __builtin_amdgcn_mfma_f32_16x16x32_bf16(a0, b0L, acc00, 0, 0, 0);
    acc01 = __builtin_amdgcn_mfma_f32_16x16x32_bf16(a0, b1L, acc01, 0, 0, 0);
    acc10 = __builtin_amdgcn_mfma_f32_16x16x32_bf16(a1, b0L, acc10, 0, 0, 0);
    acc11 = __builtin_amdgcn_mfma_f32_16x16x32_bf16(a1, b1L, acc11, 0, 0, 0);
  }
#pragma unroll
  for (int reg = 0; reg < 4; reg++) {
    const int row = q * 4 + reg;
    float v00 = acc00[reg], v01 = acc01[reg], v10 = acc10[reg], v11 = acc11[reg];
    v00 = v00 > 0.f ? v00 : expm1f(v00);
    v01 = v01 > 0.f ? v01 : expm1f(v01);
    v10 = v10 > 0.f ? v10 : expm1f(v10);
    v11 = v11 > 0.f ? v11 : expm1f(v11);
    float* o0 = out + (base + i0 + row) * (long)ostride + ocoff + n0 + m16;
    float* o1 = out + (base + i0 + 16 + row) * (long)ostride + ocoff + n0 + m16;
    o0[0] = v00; o0[16] = v01;
    o1[0] = v10; o1[16] = v11;
  }
}

// ---- K3/K4: MFMA GEMM, C = A[32768,K] @ BT^T, 32 rows x 128 cols/block.
// A fp32 -> bf16 hi/lo during LDS staging; B pre-split via wt_prep.
// MODE 0: emit whT hi/lo + src/dst.  MODE 1: +bias +leaky fp32 store. ----
template<int K, int KC, int MODE>
__global__ __launch_bounds__(256) void mfma_gemm(
    const float* __restrict__ A,
    const ushort* __restrict__ BTH, const ushort* __restrict__ BTL,
    const float* __restrict__ bias, float* __restrict__ outF,
    ushort* __restrict__ whtH, ushort* __restrict__ whtL,
    const float* __restrict__ avec, float* __restrict__ src, float* __restrict__ dst,
    const int ostride)
{
  constexpr int KP = KC + 8;
  __shared__ ushort AsH[32][KP];
  __shared__ ushort AsL[32][KP];
  __shared__ float sredS[4][32], sredD[4][32];
  const int t = threadIdx.x;
  const long row0 = (long)blockIdx.x * 32;
  const int ncoff = (MODE == 1) ? blockIdx.y * 128 : 0;

  const int wv = t >> 6, lane = t & 63;
  const int m16 = lane & 15, q = lane >> 4;
  const int n0 = wv * 32;
  const ushort* __restrict__ bh0 = BTH + (long)(ncoff + n0 + m16) * K;
  const ushort* __restrict__ bl0 = BTL + (long)(ncoff + n0 + m16) * K;

  f32x4 acc[2][2];
#pragma unroll
  for (int m = 0; m < 2; m++)
#pragma unroll
    for (int n = 0; n < 2; n++) acc[m][n] = (f32x4){0.f, 0.f, 0.f, 0.f};

  for (int kc = 0; kc < K; kc += KC) {
    constexpr int NIT = (32 * KC / 4) / 256;
#pragma unroll
    for (int it = 0; it < NIT; it++) {
      const int idx = t + it * 256;
      const int r = idx / (KC / 4), k4 = idx % (KC / 4);
      const float4 v = *(const float4*)&A[(row0 + r) * (long)K + kc + k4 * 4];
      split_store4(&AsH[r][k4 * 4], &AsL[r][k4 * 4], v.x, v.y, v.z, v.w);
    }
    __syncthreads();
#pragma unroll
    for (int ks = 0; ks < KC / 32; ks++) {
      const int k0 = ks * 32 + q * 8;
      const s16x8 a0H = *(const s16x8*)&AsH[m16][k0];
      const s16x8 a0L = *(const s16x8*)&AsL[m16][k0];
      const s16x8 a1H = *(const s16x8*)&AsH[16 + m16][k0];
      const s16x8 a1L = *(const s16x8*)&AsL[16 + m16][k0];
      const int kg = kc + k0;
      const s16x8 b0H = *(const s16x8*)&bh0[kg];
      const s16x8 b0L = *(const s16x8*)&bl0[kg];
      const s16x8 b1H = *(const s16x8*)&bh0[16 * K + kg];
      const s16x8 b1L = *(const s16x8*)&bl0[16 * K + kg];
      acc[0][0] = __builtin_amdgcn_mfma_f32_16x16x32_bf16(a0H, b0H, acc[0][0], 0, 0, 0);
      acc[0][1] = __builtin_amdgcn_mfma_f32_16x16x32_bf16(a0H, b1H, acc[0][1], 0, 0, 0);
      acc[1][0] = __builtin_amdgcn_mfma_f32_16x16x32_bf16(a1H, b0H, acc[1][0], 0, 0, 0);
      acc[1][1] = __builtin_amdgcn_mfma_f32_16x16x32_bf16(a1H, b1H, acc[1][1], 0, 0, 0);
      acc[0][0] = __builtin_amdgcn_mfma_f32_16x16x32_bf16(a0L, b0H, acc[0][0], 0, 0, 0);
      acc[0][1] = __builtin_amdgcn_mfma_f32_16x16x32_bf16(a0L, b1H, acc[0][1], 0, 0, 0);
      acc[1][0] = __builtin_amdgcn_mfma_f32_16x16x32_bf16(a1L, b0H, acc[1][0], 0, 0, 0);
      acc[1][1] = __builtin_amdgcn_mfma_f32_16x16x32_bf16(a1L, b1H, acc[1][1], 0, 0, 0);
      acc[0][0] = __builtin_amdgcn_mfma_f32_16x16x32_bf16(a0H, b0L, acc[0][0], 0, 0, 0);
      acc[0][1] = __builtin_amdgcn_mfma_f32_16x16x32_bf16(a0H, b1L, acc[0][1], 0, 0, 0);
      acc[1][0] = __builtin_amdgcn_mfma_f32_16x16x32_bf16(a1H, b0L, acc[1][0], 0, 0, 0);
      acc[1][1] = __builtin_amdgcn_mfma_f32_16x16x32_bf16(a1H, b1L, acc[1][1], 0, 0, 0);
    }
    __syncthreads();
  }

  if (MODE == 0) {
    // whT hi/lo store: whtH[b][c][j]
    const long b = row0 >> 9;
    const int iloc = (int)(row0 & 511);
#pragma unroll
    for (int m = 0; m < 2; m++)
#pragma unroll
      for (int n = 0; n < 2; n++) {
        const int c = n0 + n * 16 + m16;
        const long o = b * 65536 + (long)c * 512 + iloc + m * 16 + q * 4;
        const f32x4 v = acc[m][n];
        split_store4(&whtH[o], &whtL[o], v[0], v[1], v[2], v[3]);
      }
    // fused src/dst: reduce over cols (16 lanes x 2 n-tiles per wave, 4 waves)
    const float a10 = avec[n0 + m16], a11 = avec[n0 + 16 + m16];
    const float a20 = avec[128 + n0 + m16], a21 = avec[128 + n0 + 16 + m16];
#pragma unroll
    for (int m = 0; m < 2; m++) {
#pragma unroll
      for (int reg = 0; reg < 4; reg++) {
        float s = acc[m][0][reg] * a10 + acc[m][1][reg] * a11;
        float d = acc[m][0][reg] * a20 + acc[m][1][reg] * a21;
#pragma unroll
        for (int w = 1; w < 16; w <<= 1) {
          s += __shfl_xor(s, w, 64);
          d += __shfl_xor(d, w, 64);
        }
        if (m16 == 0) {
          const int row = m * 16 + q * 4 + reg;
          sredS[wv][row] = s;
          sredD[wv][row] = d;
        }
      }
    }
    __syncthreads();
    if (t < 32) {
      const float s = sredS[0][t] + sredS[1][t] + sredS[2][t] + sredS[3][t];
      const float d = sredD[0][t] + sredD[1][t] + sredD[2][t] + sredD[3][t];
      src[row0 + t] = s;
      dst[row0 + t] = d;
    }
  } else {
#pragma unroll
    for (int m = 0; m < 2; m++)
#pragma unroll
      for (int n = 0; n < 2; n++) {
        const int c = ncoff + n0 + n * 16 + m16;
        const float bv = bias[c];
#pragma unroll
        for (int reg = 0; reg < 4; reg++) {
          float v = acc[m][n][reg] + bv;
          v = fmaxf(v, ALPHA * v);
          outF[(row0 + m * 16 + q * 4 + reg) * (long)ostride + c] = v;
        }
      }
  }
}

extern "C" void kernel_launch(void* const* d_in, const int* in_sizes, int n_in,
                              void* d_out, int out_size, void* d_ws, size_t ws_size,
                              hipStream_t stream) {
  const float* compound = (const float*)d_in[0];
  const int*   adj      = (const int*)d_in[1];
  const float* W_stack  = (const float*)d_in[2];
  const float* a_stack  = (const float*)d_in[3];
  const float* W_out    = (const float*)d_in[4];
  const float* a_out    = (const float*)d_in[5];
  const float* Wc       = (const float*)d_in[6];
  const float* bc       = (const float*)d_in[7];
  float* out = (float*)d_out;

  ushort* whtH = (ushort*)d_ws;                       // 8 MB
  ushort* whtL = whtH + 4194304;                      // 8 MB
  ushort* Pg   = whtL + 4194304;                      // 33.5 MB
  float* f     = (float*)d_ws;
  float* src   = f + 12582912;
  float* dstv  = src + 32768;
  float* multi = dstv + 32768;                        // 12,582,912 floats
  float* x     = multi;                               // aliases multi head
  unsigned* mask = (unsigned*)d_out;                  // 2.1 MB, dead until final GEMM
  ushort* WoT_H = Pg;                                 // parked in Pg: valid agg-3 -> scores-4
  ushort* WoT_L = Pg + 49152;
  ushort* WcT_H = (ushort*)(multi + 5000000);         // parked in dead multi tail
  ushort* WcT_L = WcT_H + 32768;

  maskprep<<<2048, 256, 0, stream>>>(adj, mask);
  for (int l = 0; l < 3; l++) {
    wh_small<<<1024, 256, 0, stream>>>(
        compound, W_stack + (long)l * 34 * 128, a_stack + (long)l * 256,
        whtH, whtL, src, dstv);
    scores_kernel<<<dim3(32, 64), 256, 0, stream>>>(mask, src, dstv, Pg);
    agg_kernel<<<dim3(16, 64), 256, 0, stream>>>(
        Pg, whtH, whtL, multi, 384, l * 128);
  }
  // layer 4: Wh = multi @ W_out  (MFMA, emits whT + src/dst)
  wt_prep<<<192, 256, 0, stream>>>(W_out, WoT_H, WoT_L, 384, 128);
  mfma_gemm<384, 192, 0><<<1024, 256, 0, stream>>>(
      multi, WoT_H, WoT_L, nullptr, nullptr, whtH, whtL, a_out, src, dstv, 0);
  scores_kernel<<<dim3(32, 64), 256, 0, stream>>>(mask, src, dstv, Pg);
  agg_kernel<<<dim3(16, 64), 256, 0, stream>>>(Pg, whtH, whtL, x, 128, 0);
  // final: out = leaky(x @ Wc + bc)  (MFMA)
  wt_prep<<<128, 256, 0, stream>>>(Wc, WcT_H, WcT_L, 128, 256);
  mfma_gemm<128, 128, 1><<<dim3(1024, 2), 256, 0, stream>>>(
      x, WcT_H, WcT_L, bc, out, nullptr, nullptr, nullptr, nullptr, nullptr, 256);
}